// Round 3
// baseline (52507.605 us; speedup 1.0000x reference)
//
#include <hip/hip_runtime.h>
#include <hip/hip_cooperative_groups.h>

namespace cg = cooperative_groups;

// ---------------------------------------------------------------------------
// LayerNorm-LSTM (depth=2) + FC, MI355X. Split-bf16 (hi/lo) 3-term MFMA.
// Round 3: single persistent cooperative kernel for the whole recurrence,
// wavefront-pipelined layers (LAG=16), in-kernel chunked ih-projections.
// ---------------------------------------------------------------------------

typedef __attribute__((ext_vector_type(8))) short short8;
typedef __attribute__((ext_vector_type(8))) __bf16 bf16x8;
typedef __attribute__((ext_vector_type(4))) float f32x4;
typedef __attribute__((ext_vector_type(4))) unsigned short us4;

#define B_ 64
#define T_ 512
#define D_ 1024
#define H_ 1024
#define FH_ 4096
#define LAG_ 16
#define NS_ (T_ + LAG_)        // 528 macro-steps

static __device__ __forceinline__ unsigned short f2bf(float f) {
  unsigned int u = __builtin_bit_cast(unsigned int, f);
  u += 0x7FFFu + ((u >> 16) & 1u);   // round-to-nearest-even
  return (unsigned short)(u >> 16);
}
static __device__ __forceinline__ float bf2f(unsigned short u) {
  unsigned int x = ((unsigned int)u) << 16;
  return __builtin_bit_cast(float, x);
}

// ---------------- split-cast fp32 -> (hi, lo) bf16 ----------------
__global__ void cast_split_k(const float4* __restrict__ in,
                             us4* __restrict__ hi, us4* __restrict__ lo, int n4) {
  int i = blockIdx.x * 256 + threadIdx.x;
  if (i < n4) {
    float4 v = in[i];
    us4 h, l;
    h[0] = f2bf(v.x); l[0] = f2bf(v.x - bf2f(h[0]));
    h[1] = f2bf(v.y); l[1] = f2bf(v.y - bf2f(h[1]));
    h[2] = f2bf(v.z); l[2] = f2bf(v.z - bf2f(h[2]));
    h[3] = f2bf(v.w); l[3] = f2bf(v.w - bf2f(h[3]));
    hi[i] = h; lo[i] = l;
  }
}

// ------ transpose-split input [B][T][D] f32 -> [T][B][D] (hi, lo) bf16 -----
__global__ void transpose_split_k(const float4* __restrict__ x,
                                  us4* __restrict__ hi, us4* __restrict__ lo) {
  int i = blockIdx.x * 256 + threadIdx.x;   // over T*B*D/4
  int d4  = i & 255;
  int rem = i >> 8;
  int b = rem & 63;
  int t = rem >> 6;
  float4 v = x[((size_t)(b * T_ + t) << 8) + d4];
  us4 h, l;
  h[0] = f2bf(v.x); l[0] = f2bf(v.x - bf2f(h[0]));
  h[1] = f2bf(v.y); l[1] = f2bf(v.y - bf2f(h[1]));
  h[2] = f2bf(v.z); l[2] = f2bf(v.z - bf2f(h[2]));
  h[3] = f2bf(v.w); l[3] = f2bf(v.w - bf2f(h[3]));
  size_t o = ((size_t)(t * B_ + b) << 8) + d4;
  hi[o] = h; lo[o] = l;
}

// ---------------- FC GEMM (3-term split, 256 thr, 128x128 tile) ----------
__global__ __launch_bounds__(256) void gemm3_fc_k(
    const unsigned short* __restrict__ Ahi, const unsigned short* __restrict__ Alo,
    const unsigned short* __restrict__ Whi, const unsigned short* __restrict__ Wlo,
    const float* __restrict__ bias, float* __restrict__ out, int K, int N) {
  __shared__ unsigned short lAh[128 * 40];
  __shared__ unsigned short lAl[128 * 40];
  __shared__ unsigned short lWh[128 * 40];
  __shared__ unsigned short lWl[128 * 40];
  int tid = threadIdx.x;
  int l = tid & 63, w = tid >> 6;
  int r0 = blockIdx.y * 128, c0 = blockIdx.x * 128;
  int wr = (w >> 1) * 64, wc = (w & 1) * 64;
  int lr = l & 15, lk = (l >> 4) * 8;
  f32x4 acc[4][4] = {};
  int srow = tid >> 2;
  int scc  = (tid & 3) * 8;

  for (int kt = 0; kt < K; kt += 32) {
#pragma unroll
    for (int i = 0; i < 2; ++i) {
      int row = srow + i * 64;
      size_t aoff = (size_t)(r0 + row) * K + kt + scc;
      size_t woff = (size_t)(c0 + row) * K + kt + scc;
      *(short8*)&lAh[row * 40 + scc] = *(const short8*)(Ahi + aoff);
      *(short8*)&lAl[row * 40 + scc] = *(const short8*)(Alo + aoff);
      *(short8*)&lWh[row * 40 + scc] = *(const short8*)(Whi + woff);
      *(short8*)&lWl[row * 40 + scc] = *(const short8*)(Wlo + woff);
    }
    __syncthreads();
    bf16x8 ah[4], al[4], bh[4], bl[4];
#pragma unroll
    for (int mi = 0; mi < 4; ++mi) {
      ah[mi] = *(bf16x8*)&lAh[(wr + mi * 16 + lr) * 40 + lk];
      al[mi] = *(bf16x8*)&lAl[(wr + mi * 16 + lr) * 40 + lk];
    }
#pragma unroll
    for (int ni = 0; ni < 4; ++ni) {
      bh[ni] = *(bf16x8*)&lWh[(wc + ni * 16 + lr) * 40 + lk];
      bl[ni] = *(bf16x8*)&lWl[(wc + ni * 16 + lr) * 40 + lk];
    }
#pragma unroll
    for (int mi = 0; mi < 4; ++mi)
#pragma unroll
      for (int ni = 0; ni < 4; ++ni) {
        acc[mi][ni] = __builtin_amdgcn_mfma_f32_16x16x32_bf16(ah[mi], bh[ni], acc[mi][ni], 0, 0, 0);
        acc[mi][ni] = __builtin_amdgcn_mfma_f32_16x16x32_bf16(ah[mi], bl[ni], acc[mi][ni], 0, 0, 0);
        acc[mi][ni] = __builtin_amdgcn_mfma_f32_16x16x32_bf16(al[mi], bh[ni], acc[mi][ni], 0, 0, 0);
      }
    __syncthreads();
  }

#pragma unroll
  for (int mi = 0; mi < 4; ++mi)
#pragma unroll
    for (int ni = 0; ni < 4; ++ni)
#pragma unroll
      for (int reg = 0; reg < 4; ++reg) {
        int r = r0 + wr + mi * 16 + (l >> 4) * 4 + reg;
        int c = c0 + wc + ni * 16 + lr;
        float v = acc[mi][ni][reg] + bias[c];
        int b = r & 63, t = r >> 6;
        out[((size_t)b * T_ + t) * (size_t)N + c] = v;   // [b][t][c]
      }
}

// ---------------- persistent LSTM kernel ----------------
struct LP {
  unsigned short *XYhi, *XYlo;                 // [T][64][1024] X -> Y0 -> Y1
  const unsigned short *wihHi, *wihLo, *whhHi, *whhLo;
  const float *bih, *bhh, *gih, *beih, *ghh, *behh, *gho, *beho;
  float *P0, *P1;                              // [16][64][4096] fp32
  float *G;                                    // [2][64][4096] fp32
  unsigned short *hH, *hL;                     // [2][64][1024]
  float *cst;                                  // [2][64][1024]
};

__device__ __forceinline__ void wave_red(float& v) {
#pragma unroll
  for (int o = 32; o; o >>= 1) v += __shfl_down(v, o);
}

__global__ __launch_bounds__(512) void lstm_persist_k(LP p) {
  cg::grid_group grid = cg::this_grid();
  __shared__ unsigned short lAh[128 * 40];
  __shared__ unsigned short lAl[128 * 40];
  __shared__ unsigned short lWh[128 * 40];
  __shared__ unsigned short lWl[128 * 40];
  __shared__ float red[32];

  const int tid = threadIdx.x;
  const int blk = blockIdx.x;
  const int l = tid & 63, w = tid >> 6;
  const int lr = l & 15, lk = (l >> 4) * 8;

  for (int s = 0; s < NS_; ++s) {
    // ================= chunk phase (every 16 steps) =================
    if ((s & 15) == 0) {
      int nt0 = (s < T_) ? 256 : 0;
      int ntT = nt0 + ((s >= LAG_) ? 256 : 0);
      for (int tile = blk; tile < ntT; tile += 256) {
        int isP0 = (tile < nt0) ? 1 : 0;
        int tt = isP0 ? tile : tile - nt0;
        int c0 = (tt & 31) * 128, r0 = (tt >> 5) * 128;
        const unsigned short* Ahi;
        const unsigned short* Alo;
        const unsigned short* Whi;
        const unsigned short* Wlo;
        const float* bias;
        float* outp;
        if (isP0) {
          Ahi = p.XYhi + (size_t)s * 65536;   // rows t=s..s+15 (X values)
          Alo = p.XYlo + (size_t)s * 65536;
          Whi = p.wihHi; Wlo = p.wihLo; bias = p.bih; outp = p.P0;
        } else {
          Ahi = p.XYhi + (size_t)(s - LAG_) * 65536;  // rows = Y0 outputs
          Alo = p.XYlo + (size_t)(s - LAG_) * 65536;
          Whi = p.wihHi + (1 << 22); Wlo = p.wihLo + (1 << 22);
          bias = p.bih + FH_; outp = p.P1;
        }
        // 128x128 tile, 8 waves as 2x4 grid of 64x32 sub-tiles, BK=32, K=1024
        int wr = (w >> 2) * 64, wc = (w & 3) * 32;
        f32x4 acc[4][2] = {};
        int srow = tid >> 2;          // 0..127
        int scc  = (tid & 3) * 8;
        for (int kt = 0; kt < 1024; kt += 32) {
          size_t ao = (size_t)(r0 + srow) * 1024 + kt + scc;
          size_t wo = (size_t)(c0 + srow) * 1024 + kt + scc;
          *(short8*)&lAh[srow * 40 + scc] = *(const short8*)(Ahi + ao);
          *(short8*)&lAl[srow * 40 + scc] = *(const short8*)(Alo + ao);
          *(short8*)&lWh[srow * 40 + scc] = *(const short8*)(Whi + wo);
          *(short8*)&lWl[srow * 40 + scc] = *(const short8*)(Wlo + wo);
          __syncthreads();
          bf16x8 ah[4], al[4], bh[2], bl[2];
#pragma unroll
          for (int mi = 0; mi < 4; ++mi) {
            ah[mi] = *(bf16x8*)&lAh[(wr + mi * 16 + lr) * 40 + lk];
            al[mi] = *(bf16x8*)&lAl[(wr + mi * 16 + lr) * 40 + lk];
          }
#pragma unroll
          for (int ni = 0; ni < 2; ++ni) {
            bh[ni] = *(bf16x8*)&lWh[(wc + ni * 16 + lr) * 40 + lk];
            bl[ni] = *(bf16x8*)&lWl[(wc + ni * 16 + lr) * 40 + lk];
          }
#pragma unroll
          for (int mi = 0; mi < 4; ++mi)
#pragma unroll
            for (int ni = 0; ni < 2; ++ni) {
              acc[mi][ni] = __builtin_amdgcn_mfma_f32_16x16x32_bf16(ah[mi], bh[ni], acc[mi][ni], 0, 0, 0);
              acc[mi][ni] = __builtin_amdgcn_mfma_f32_16x16x32_bf16(ah[mi], bl[ni], acc[mi][ni], 0, 0, 0);
              acc[mi][ni] = __builtin_amdgcn_mfma_f32_16x16x32_bf16(al[mi], bh[ni], acc[mi][ni], 0, 0, 0);
            }
          __syncthreads();
        }
#pragma unroll
        for (int mi = 0; mi < 4; ++mi)
#pragma unroll
          for (int ni = 0; ni < 2; ++ni)
#pragma unroll
            for (int reg = 0; reg < 4; ++reg) {
              int row = r0 + wr + mi * 16 + (l >> 4) * 4 + reg;
              int col = c0 + wc + ni * 16 + lr;
              outp[(size_t)row * FH_ + col] = acc[mi][ni][reg] + bias[col];
            }
      }
      grid.sync();
    }

    // ================= step hh-GEMM phase =================
    {
      int layer = blk >> 7;                     // 0..127 -> l0, 128..255 -> l1
      bool act = layer ? (s >= LAG_) : (s < T_);
      if (act) {
        int jb = blk & 127;
        int n0 = jb * 32 + (w >> 2) * 16;       // colfrag from wave
        int m0 = (w & 3) * 16;                  // row group from wave
        const unsigned short* hHb = p.hH + layer * 65536;
        const unsigned short* hLb = p.hL + layer * 65536;
        const unsigned short* Whi = p.whhHi + ((size_t)layer << 22);
        const unsigned short* Wlo = p.whhLo + ((size_t)layer << 22);
        f32x4 acc = {};
#pragma unroll 8
        for (int kt = 0; kt < 1024; kt += 32) {
          int k = kt + lk;
          bf16x8 ah = __builtin_bit_cast(bf16x8, *(const short8*)(hHb + (m0 + lr) * 1024 + k));
          bf16x8 al = __builtin_bit_cast(bf16x8, *(const short8*)(hLb + (m0 + lr) * 1024 + k));
          bf16x8 bh = __builtin_bit_cast(bf16x8, *(const short8*)(Whi + (size_t)(n0 + lr) * 1024 + k));
          bf16x8 bl = __builtin_bit_cast(bf16x8, *(const short8*)(Wlo + (size_t)(n0 + lr) * 1024 + k));
          acc = __builtin_amdgcn_mfma_f32_16x16x32_bf16(ah, bh, acc, 0, 0, 0);
          acc = __builtin_amdgcn_mfma_f32_16x16x32_bf16(ah, bl, acc, 0, 0, 0);
          acc = __builtin_amdgcn_mfma_f32_16x16x32_bf16(al, bh, acc, 0, 0, 0);
        }
        float* Gb = p.G + layer * (64 * FH_);
#pragma unroll
        for (int reg = 0; reg < 4; ++reg) {
          int row = m0 + (l >> 4) * 4 + reg;
          Gb[(size_t)row * FH_ + n0 + lr] = acc[reg];
        }
      }
    }
    grid.sync();

    // ================= pointwise phase =================
    if (blk < 128) {
      int layer = blk >> 6;
      bool act = layer ? (s >= LAG_) : (s < T_);
      if (act) {
        int r = blk & 63;
        int slot = s & 15;
        const float* Pr = (layer ? p.P1 : p.P0) + (size_t)slot * B_ * FH_ + (size_t)r * FH_;
        const float* Gr = p.G + layer * (64 * FH_) + (size_t)r * FH_;
        const float* bhh = p.bhh + layer * FH_;
        const float* gih = p.gih + layer * FH_;
        const float* beih= p.beih + layer * FH_;
        const float* ghh = p.ghh + layer * FH_;
        const float* behh= p.behh + layer * FH_;
        const float* gho = p.gho + layer * H_;
        const float* beho= p.beho + layer * H_;
        float* crow = p.cst + layer * 65536 + (size_t)r * H_;
        int wv = tid >> 6, ln = tid & 63;

        float ihp[8], hhp[8];
        float s1 = 0, q1 = 0, s2 = 0, q2 = 0;
#pragma unroll
        for (int st = 0; st < 8; ++st) {
          int n = tid + 512 * st;
          float a = Pr[n];
          float b = Gr[n] + bhh[n];
          ihp[st] = a; hhp[st] = b;
          s1 += a; q1 += a * a; s2 += b; q2 += b * b;
        }
        wave_red(s1); wave_red(q1); wave_red(s2); wave_red(q2);
        if (ln == 0) { red[wv*4] = s1; red[wv*4+1] = q1; red[wv*4+2] = s2; red[wv*4+3] = q2; }
        __syncthreads();
        s1 = 0; q1 = 0; s2 = 0; q2 = 0;
#pragma unroll
        for (int k = 0; k < 8; ++k) {
          s1 += red[k*4]; q1 += red[k*4+1]; s2 += red[k*4+2]; q2 += red[k*4+3];
        }
        __syncthreads();

        const float inv4h = 1.0f / 4096.0f;
        float m1 = s1 * inv4h, m2 = s2 * inv4h;
        float i1 = rsqrtf(q1 * inv4h - m1 * m1 + 1e-5f);
        float i2 = rsqrtf(q2 * inv4h - m2 * m2 + 1e-5f);

        float pre[8];
#pragma unroll
        for (int st = 0; st < 8; ++st) {
          int n = tid + 512 * st;
          pre[st] = gih[n] * (ihp[st] - m1) * i1 + beih[n] + ghh[n] * (hhp[st] - m2) * i2 + behh[n];
        }

        float cn[2], og[2];
        float s3 = 0, q3 = 0;
#pragma unroll
        for (int u = 0; u < 2; ++u) {
          int hidx = tid + 512 * u;
          float iG = 1.0f / (1.0f + __expf(-pre[u]));
          float fG = 1.0f / (1.0f + __expf(-pre[2 + u]));
          float oG = 1.0f / (1.0f + __expf(-pre[4 + u]));
          float gG = tanhf(pre[6 + u]);
          float c = fG * crow[hidx] + iG * gG;
          crow[hidx] = c;
          cn[u] = c; og[u] = oG;
          s3 += c; q3 += c * c;
        }
        wave_red(s3); wave_red(q3);
        if (ln == 0) { red[wv*4] = s3; red[wv*4+1] = q3; }
        __syncthreads();
        s3 = 0; q3 = 0;
#pragma unroll
        for (int k = 0; k < 8; ++k) { s3 += red[k*4]; q3 += red[k*4+1]; }

        const float invh = 1.0f / 1024.0f;
        float m3 = s3 * invh;
        float i3 = rsqrtf(q3 * invh - m3 * m3 + 1e-5f);
        int tY = layer ? (s - LAG_) : s;
        unsigned short* hHb = p.hH + layer * 65536 + (size_t)r * H_;
        unsigned short* hLb = p.hL + layer * 65536 + (size_t)r * H_;
        unsigned short* YH = p.XYhi + (size_t)tY * 65536 + (size_t)r * H_;
        unsigned short* YL = p.XYlo + (size_t)tY * 65536 + (size_t)r * H_;
#pragma unroll
        for (int u = 0; u < 2; ++u) {
          int hidx = tid + 512 * u;
          float hy = og[u] * tanhf((cn[u] - m3) * i3 * gho[hidx] + beho[hidx]);
          unsigned short hv = f2bf(hy);
          unsigned short lv = f2bf(hy - bf2f(hv));
          hHb[hidx] = hv; hLb[hidx] = lv;
          YH[hidx] = hv;  YL[hidx] = lv;
        }
      }
    }
    grid.sync();
  }
}

// ---------------------------------------------------------------------------
extern "C" void kernel_launch(void* const* d_in, const int* in_sizes, int n_in,
                              void* d_out, int out_size, void* d_ws, size_t ws_size,
                              hipStream_t stream) {
  const float* x    = (const float*)d_in[0];
  const float* w_ih = (const float*)d_in[1];
  const float* b_ih = (const float*)d_in[2];
  const float* w_hh = (const float*)d_in[3];
  const float* b_hh = (const float*)d_in[4];
  const float* g_ih = (const float*)d_in[5];
  const float* be_ih= (const float*)d_in[6];
  const float* g_hh = (const float*)d_in[7];
  const float* be_hh= (const float*)d_in[8];
  const float* g_ho = (const float*)d_in[9];
  const float* be_ho= (const float*)d_in[10];
  const float* fc_w = (const float*)d_in[11];
  const float* fc_b = (const float*)d_in[12];
  float* out = (float*)d_out;
  (void)ws_size; (void)in_sizes; (void)n_in; (void)out_size;

  // workspace carve-up (~231 MB)
  char* wsb = (char*)d_ws;
  size_t off = 0;
  unsigned short* wihHi = (unsigned short*)(wsb + off); off += 16777216;
  unsigned short* wihLo = (unsigned short*)(wsb + off); off += 16777216;
  unsigned short* whhHi = (unsigned short*)(wsb + off); off += 16777216;
  unsigned short* whhLo = (unsigned short*)(wsb + off); off += 16777216;
  unsigned short* fcHi  = (unsigned short*)(wsb + off); off += 2097152;
  unsigned short* fcLo  = (unsigned short*)(wsb + off); off += 2097152;
  unsigned short* XYhi  = (unsigned short*)(wsb + off); off += 67108864;
  unsigned short* XYlo  = (unsigned short*)(wsb + off); off += 67108864;
  float* P0             = (float*)(wsb + off); off += (size_t)16 * B_ * FH_ * 4; // 16 MB
  float* P1             = (float*)(wsb + off); off += (size_t)16 * B_ * FH_ * 4; // 16 MB
  float* G              = (float*)(wsb + off); off += (size_t)2 * B_ * FH_ * 4;  // 2 MB
  unsigned short* hH    = (unsigned short*)(wsb + off); off += 262144;
  unsigned short* hL    = (unsigned short*)(wsb + off); off += 262144;
  float* cst            = (float*)(wsb + off); off += 524288;

  // --- splits ---
  {
    int n4 = 2 * FH_ * D_ / 4;
    cast_split_k<<<(n4 + 255) / 256, 256, 0, stream>>>((const float4*)w_ih, (us4*)wihHi, (us4*)wihLo, n4);
    cast_split_k<<<(n4 + 255) / 256, 256, 0, stream>>>((const float4*)w_hh, (us4*)whhHi, (us4*)whhLo, n4);
    int nf = H_ * H_ / 4;
    cast_split_k<<<(nf + 255) / 256, 256, 0, stream>>>((const float4*)fc_w, (us4*)fcHi, (us4*)fcLo, nf);
    int nx = T_ * B_ * D_ / 4;
    transpose_split_k<<<nx / 256, 256, 0, stream>>>((const float4*)x, (us4*)XYhi, (us4*)XYlo);
  }

  // --- state init ---
  hipMemsetAsync(hH, 0, 262144, stream);
  hipMemsetAsync(hL, 0, 262144, stream);
  hipMemsetAsync(cst, 0, 524288, stream);

  // --- persistent cooperative recurrence ---
  {
    LP prm;
    prm.XYhi = XYhi; prm.XYlo = XYlo;
    prm.wihHi = wihHi; prm.wihLo = wihLo; prm.whhHi = whhHi; prm.whhLo = whhLo;
    prm.bih = b_ih; prm.bhh = b_hh; prm.gih = g_ih; prm.beih = be_ih;
    prm.ghh = g_hh; prm.behh = be_hh; prm.gho = g_ho; prm.beho = be_ho;
    prm.P0 = P0; prm.P1 = P1; prm.G = G;
    prm.hH = hH; prm.hL = hL; prm.cst = cst;
    void* args[] = { &prm };
    hipLaunchCooperativeKernel(reinterpret_cast<void*>(lstm_persist_k),
                               dim3(256), dim3(512), args, 0, stream);
  }

  // --- final FC: out[b][t][c] = Y1[t*B+b,:]·fc_w[c,:] + fc_b ---
  gemm3_fc_k<<<dim3(H_ / 128, (T_ * B_) / 128), 256, 0, stream>>>(
      XYhi, XYlo, fcHi, fcLo, fc_b, out, H_, H_);
}

// Round 4
// 46998.148 us; speedup vs baseline: 1.1172x; 1.1172x over previous
//
#include <hip/hip_runtime.h>
#include <hip/hip_cooperative_groups.h>

namespace cg = cooperative_groups;

// ---------------------------------------------------------------------------
// LayerNorm-LSTM (depth=2) + FC, MI355X. Split-bf16 (hi/lo) 3-term MFMA.
// Round 4: persistent cooperative kernel with Whh held in LDS (fragment-order,
// 128 KB/block) for the whole recurrence -> per-step HBM traffic ~0.
// ---------------------------------------------------------------------------

typedef __attribute__((ext_vector_type(8))) short short8;
typedef __attribute__((ext_vector_type(8))) __bf16 bf16x8;
typedef __attribute__((ext_vector_type(4))) float f32x4;
typedef __attribute__((ext_vector_type(4))) unsigned short us4;

#define B_ 64
#define T_ 512
#define D_ 1024
#define H_ 1024
#define FH_ 4096
#define LAG_ 16
#define NS_ (T_ + LAG_)        // 528 macro-steps

// dynamic LDS layout (bytes)
#define L_WHH   0          // 131072: Whh slice, fragment-order, hi then lo
#define L_LAH   131072     // 10240: chunk A-hi stage (128 x 40 shorts)
#define L_LAL   141312     // 10240
#define L_LWH   151552     // 5120:  chunk W-hi stage (64 x 40 shorts)
#define L_LWL   156672     // 5120
#define L_RED   161792     // 128:   pointwise reduction scratch
#define SMEM_TOTAL 161920

static __device__ __forceinline__ unsigned short f2bf(float f) {
  unsigned int u = __builtin_bit_cast(unsigned int, f);
  u += 0x7FFFu + ((u >> 16) & 1u);   // round-to-nearest-even
  return (unsigned short)(u >> 16);
}
static __device__ __forceinline__ float bf2f(unsigned short u) {
  unsigned int x = ((unsigned int)u) << 16;
  return __builtin_bit_cast(float, x);
}

// ---------------- split-cast fp32 -> (hi, lo) bf16 ----------------
__global__ void cast_split_k(const float4* __restrict__ in,
                             us4* __restrict__ hi, us4* __restrict__ lo, int n4) {
  int i = blockIdx.x * 256 + threadIdx.x;
  if (i < n4) {
    float4 v = in[i];
    us4 h, l;
    h[0] = f2bf(v.x); l[0] = f2bf(v.x - bf2f(h[0]));
    h[1] = f2bf(v.y); l[1] = f2bf(v.y - bf2f(h[1]));
    h[2] = f2bf(v.z); l[2] = f2bf(v.z - bf2f(h[2]));
    h[3] = f2bf(v.w); l[3] = f2bf(v.w - bf2f(h[3]));
    hi[i] = h; lo[i] = l;
  }
}

// ------ transpose-split input [B][T][D] f32 -> [T][B][D] (hi, lo) bf16 -----
__global__ void transpose_split_k(const float4* __restrict__ x,
                                  us4* __restrict__ hi, us4* __restrict__ lo) {
  int i = blockIdx.x * 256 + threadIdx.x;   // over T*B*D/4
  int d4  = i & 255;
  int rem = i >> 8;
  int b = rem & 63;
  int t = rem >> 6;
  float4 v = x[((size_t)(b * T_ + t) << 8) + d4];
  us4 h, l;
  h[0] = f2bf(v.x); l[0] = f2bf(v.x - bf2f(h[0]));
  h[1] = f2bf(v.y); l[1] = f2bf(v.y - bf2f(h[1]));
  h[2] = f2bf(v.z); l[2] = f2bf(v.z - bf2f(h[2]));
  h[3] = f2bf(v.w); l[3] = f2bf(v.w - bf2f(h[3]));
  size_t o = ((size_t)(t * B_ + b) << 8) + d4;
  hi[o] = h; lo[o] = l;
}

// ------ rearrange Whh into per-block MFMA-B-fragment order -----------------
// frag[b][sel][g][kc][lane] (16B units): b=0..255 slice (layer=b>>7,
// colbase=(b&127)*32), sel 0=hi 1=lo, g=16-col group 0..1, kc=K-chunk 0..31,
// lane=0..63. Lane l covers W[colbase+g*16+(l&15)][kc*32+(l>>4)*8 .. +7].
__global__ void whh_frag_k(const unsigned short* __restrict__ whhHi,
                           const unsigned short* __restrict__ whhLo,
                           unsigned short* __restrict__ frag) {
  int i = blockIdx.x * 256 + threadIdx.x;   // 2,097,152 16B-chunks
  int b    = i >> 13;
  int rem  = i & 8191;
  int sel  = rem >> 12;
  int rem2 = rem & 4095;
  int g    = rem2 >> 11;
  int rem3 = rem2 & 2047;
  int kc   = rem3 >> 6;
  int lane = rem3 & 63;
  int layer = b >> 7;
  int col = (b & 127) * 32 + g * 16 + (lane & 15);
  int kof = kc * 32 + (lane >> 4) * 8;
  const unsigned short* src = (sel ? whhLo : whhHi)
      + ((size_t)layer * FH_ + col) * 1024 + kof;
  *(short8*)(frag + (size_t)i * 8) = *(const short8*)src;
}

// ---------------- FC GEMM (3-term split, 256 thr, 128x128 tile) ----------
__global__ __launch_bounds__(256) void gemm3_fc_k(
    const unsigned short* __restrict__ Ahi, const unsigned short* __restrict__ Alo,
    const unsigned short* __restrict__ Whi, const unsigned short* __restrict__ Wlo,
    const float* __restrict__ bias, float* __restrict__ out, int K, int N) {
  __shared__ unsigned short lAh[128 * 40];
  __shared__ unsigned short lAl[128 * 40];
  __shared__ unsigned short lWh[128 * 40];
  __shared__ unsigned short lWl[128 * 40];
  int tid = threadIdx.x;
  int l = tid & 63, w = tid >> 6;
  int r0 = blockIdx.y * 128, c0 = blockIdx.x * 128;
  int wr = (w >> 1) * 64, wc = (w & 1) * 64;
  int lr = l & 15, lk = (l >> 4) * 8;
  f32x4 acc[4][4] = {};
  int srow = tid >> 2;
  int scc  = (tid & 3) * 8;

  for (int kt = 0; kt < K; kt += 32) {
#pragma unroll
    for (int i = 0; i < 2; ++i) {
      int row = srow + i * 64;
      size_t aoff = (size_t)(r0 + row) * K + kt + scc;
      size_t woff = (size_t)(c0 + row) * K + kt + scc;
      *(short8*)&lAh[row * 40 + scc] = *(const short8*)(Ahi + aoff);
      *(short8*)&lAl[row * 40 + scc] = *(const short8*)(Alo + aoff);
      *(short8*)&lWh[row * 40 + scc] = *(const short8*)(Whi + woff);
      *(short8*)&lWl[row * 40 + scc] = *(const short8*)(Wlo + woff);
    }
    __syncthreads();
    bf16x8 ah[4], al[4], bh[4], bl[4];
#pragma unroll
    for (int mi = 0; mi < 4; ++mi) {
      ah[mi] = *(bf16x8*)&lAh[(wr + mi * 16 + lr) * 40 + lk];
      al[mi] = *(bf16x8*)&lAl[(wr + mi * 16 + lr) * 40 + lk];
    }
#pragma unroll
    for (int ni = 0; ni < 4; ++ni) {
      bh[ni] = *(bf16x8*)&lWh[(wc + ni * 16 + lr) * 40 + lk];
      bl[ni] = *(bf16x8*)&lWl[(wc + ni * 16 + lr) * 40 + lk];
    }
#pragma unroll
    for (int mi = 0; mi < 4; ++mi)
#pragma unroll
      for (int ni = 0; ni < 4; ++ni) {
        acc[mi][ni] = __builtin_amdgcn_mfma_f32_16x16x32_bf16(ah[mi], bh[ni], acc[mi][ni], 0, 0, 0);
        acc[mi][ni] = __builtin_amdgcn_mfma_f32_16x16x32_bf16(ah[mi], bl[ni], acc[mi][ni], 0, 0, 0);
        acc[mi][ni] = __builtin_amdgcn_mfma_f32_16x16x32_bf16(al[mi], bh[ni], acc[mi][ni], 0, 0, 0);
      }
    __syncthreads();
  }

#pragma unroll
  for (int mi = 0; mi < 4; ++mi)
#pragma unroll
    for (int ni = 0; ni < 4; ++ni)
#pragma unroll
      for (int reg = 0; reg < 4; ++reg) {
        int r = r0 + wr + mi * 16 + (l >> 4) * 4 + reg;
        int c = c0 + wc + ni * 16 + lr;
        float v = acc[mi][ni][reg] + bias[c];
        int b = r & 63, t = r >> 6;
        out[((size_t)b * T_ + t) * (size_t)N + c] = v;   // [b][t][c]
      }
}

// ---------------- persistent LSTM kernel ----------------
struct LP {
  unsigned short *XYhi, *XYlo;                 // [T][64][1024] X -> Y0 -> Y1
  const unsigned short *wihHi, *wihLo;
  const unsigned short *whhFrag;               // [256][128KB] fragment-order
  const float *bih, *bhh, *gih, *beih, *ghh, *behh, *gho, *beho;
  float *P0, *P1;                              // [16][64][4096] fp32 (alias whhFrag)
  float *G;                                    // [2][64][4096] fp32
  unsigned short *hH, *hL;                     // [2][64][1024]
  float *cst;                                  // [2][64][1024]
};

__device__ __forceinline__ void wave_red(float& v) {
#pragma unroll
  for (int o = 32; o; o >>= 1) v += __shfl_down(v, o);
}

__global__ __launch_bounds__(512) void lstm_persist_k(LP p) {
  cg::grid_group grid = cg::this_grid();
  extern __shared__ char smem[];
  unsigned short* whhL = (unsigned short*)(smem + L_WHH);
  unsigned short* lAh  = (unsigned short*)(smem + L_LAH);
  unsigned short* lAl  = (unsigned short*)(smem + L_LAL);
  unsigned short* lWh  = (unsigned short*)(smem + L_LWH);
  unsigned short* lWl  = (unsigned short*)(smem + L_LWL);
  float* red           = (float*)(smem + L_RED);

  const int tid = threadIdx.x;
  const int blk = blockIdx.x;
  const int l = tid & 63, w = tid >> 6;
  const int lr = l & 15, lk = (l >> 4) * 8, lq = (l >> 4);

  // ---- prologue: copy this block's Whh slice (128 KB) into LDS ----
  {
    const short8* src = (const short8*)(p.whhFrag + (size_t)blk * 65536);
    short8* dst = (short8*)whhL;
    for (int i = tid; i < 8192; i += 512) dst[i] = src[i];
    __syncthreads();
  }
  grid.sync();   // whhFrag aliases P0/P1: all copies done before chunk writes

  for (int s = 0; s < NS_; ++s) {
    // ================= chunk ih-projection phase (every 16 steps) ==========
    if ((s & 15) == 0) {
      int half = blk >> 7;                     // 0 -> P0, 1 -> P1
      bool act = half ? (s >= LAG_) : (s < T_);
      if (act) {
        int j = blk & 127;
        int ct = j & 63;                       // coltile (64 cols)
        int rp = j >> 6;                       // rowtile pair selector
        const unsigned short* Ahi;
        const unsigned short* Alo;
        const unsigned short* Whi;
        const unsigned short* Wlo;
        const float* bias;
        float* outp;
        if (half == 0) {
          Ahi = p.XYhi + (size_t)s * 65536;
          Alo = p.XYlo + (size_t)s * 65536;
          Whi = p.wihHi; Wlo = p.wihLo; bias = p.bih; outp = p.P0;
        } else {
          Ahi = p.XYhi + (size_t)(s - LAG_) * 65536;
          Alo = p.XYlo + (size_t)(s - LAG_) * 65536;
          Whi = p.wihHi + (1 << 22); Wlo = p.wihLo + (1 << 22);
          bias = p.bih + FH_; outp = p.P1;
        }
        int c0 = ct * 64;
        for (int rt = rp * 4; rt < rp * 4 + 4; ++rt) {
          int r0 = rt * 128;
          f32x4 acc[4] = {};
          int srow = tid >> 2, scc = (tid & 3) * 8;
          for (int kt = 0; kt < 1024; kt += 32) {
            size_t ao = (size_t)(r0 + srow) * 1024 + kt + scc;
            *(short8*)&lAh[srow * 40 + scc] = *(const short8*)(Ahi + ao);
            *(short8*)&lAl[srow * 40 + scc] = *(const short8*)(Alo + ao);
            if (tid < 256) {
              int wr2 = tid >> 2, wk = (tid & 3) * 8;
              *(short8*)&lWh[wr2 * 40 + wk] = *(const short8*)(Whi + (size_t)(c0 + wr2) * 1024 + kt + wk);
            } else {
              int t2 = tid - 256; int wr2 = t2 >> 2, wk = (t2 & 3) * 8;
              *(short8*)&lWl[wr2 * 40 + wk] = *(const short8*)(Wlo + (size_t)(c0 + wr2) * 1024 + kt + wk);
            }
            __syncthreads();
            bf16x8 ah = *(bf16x8*)&lAh[(w * 16 + lr) * 40 + lk];
            bf16x8 al = *(bf16x8*)&lAl[(w * 16 + lr) * 40 + lk];
#pragma unroll
            for (int ni = 0; ni < 4; ++ni) {
              bf16x8 bh = *(bf16x8*)&lWh[(ni * 16 + lr) * 40 + lk];
              bf16x8 bl = *(bf16x8*)&lWl[(ni * 16 + lr) * 40 + lk];
              acc[ni] = __builtin_amdgcn_mfma_f32_16x16x32_bf16(ah, bh, acc[ni], 0, 0, 0);
              acc[ni] = __builtin_amdgcn_mfma_f32_16x16x32_bf16(ah, bl, acc[ni], 0, 0, 0);
              acc[ni] = __builtin_amdgcn_mfma_f32_16x16x32_bf16(al, bh, acc[ni], 0, 0, 0);
            }
            __syncthreads();
          }
#pragma unroll
          for (int ni = 0; ni < 4; ++ni)
#pragma unroll
            for (int reg = 0; reg < 4; ++reg) {
              int row = r0 + w * 16 + lq * 4 + reg;
              int col = c0 + ni * 16 + lr;
              outp[(size_t)row * FH_ + col] = acc[ni][reg] + bias[col];
            }
        }
      }
      grid.sync();
    }

    // ================= step hh-GEMM phase (Whh from LDS) =================
    {
      int layer = blk >> 7;
      bool act = layer ? (s >= LAG_) : (s < T_);
      if (act) {
        int jb = blk & 127;
        int cf = w >> 2;                       // colfrag 0..1
        int m0 = (w & 3) * 16;                 // rowfrag base
        const unsigned short* hHb = p.hH + layer * 65536;
        const unsigned short* hLb = p.hL + layer * 65536;
        const short8* wfrag = (const short8*)whhL;
        f32x4 acc = {};
#pragma unroll 8
        for (int kc = 0; kc < 32; ++kc) {
          int k = kc * 32 + lk;
          bf16x8 ah = __builtin_bit_cast(bf16x8, *(const short8*)(hHb + (m0 + lr) * 1024 + k));
          bf16x8 al = __builtin_bit_cast(bf16x8, *(const short8*)(hLb + (m0 + lr) * 1024 + k));
          bf16x8 bh = __builtin_bit_cast(bf16x8, wfrag[(cf * 32 + kc) * 64 + l]);
          bf16x8 bl = __builtin_bit_cast(bf16x8, wfrag[4096 + (cf * 32 + kc) * 64 + l]);
          acc = __builtin_amdgcn_mfma_f32_16x16x32_bf16(ah, bh, acc, 0, 0, 0);
          acc = __builtin_amdgcn_mfma_f32_16x16x32_bf16(ah, bl, acc, 0, 0, 0);
          acc = __builtin_amdgcn_mfma_f32_16x16x32_bf16(al, bh, acc, 0, 0, 0);
        }
        float* Gb = p.G + layer * (64 * FH_);
        int n0 = jb * 32 + cf * 16;
#pragma unroll
        for (int reg = 0; reg < 4; ++reg) {
          int row = m0 + lq * 4 + reg;
          Gb[(size_t)row * FH_ + n0 + lr] = acc[reg];
        }
      }
    }
    grid.sync();

    // ================= pointwise phase =================
    if (blk < 128) {
      int layer = blk >> 6;
      bool act = layer ? (s >= LAG_) : (s < T_);
      if (act) {
        int r = blk & 63;
        int slot = s & 15;
        const float* Pr = (layer ? p.P1 : p.P0) + (size_t)slot * B_ * FH_ + (size_t)r * FH_;
        const float* Gr = p.G + layer * (64 * FH_) + (size_t)r * FH_;
        const float* bhh = p.bhh + layer * FH_;
        const float* gih = p.gih + layer * FH_;
        const float* beih= p.beih + layer * FH_;
        const float* ghh = p.ghh + layer * FH_;
        const float* behh= p.behh + layer * FH_;
        const float* gho = p.gho + layer * H_;
        const float* beho= p.beho + layer * H_;
        float* crow = p.cst + layer * 65536 + (size_t)r * H_;
        int wv = tid >> 6, ln = tid & 63;

        float ihp[8], hhp[8];
        float s1 = 0, q1 = 0, s2 = 0, q2 = 0;
#pragma unroll
        for (int st = 0; st < 8; ++st) {
          int n = tid + 512 * st;
          float a = Pr[n];
          float b = Gr[n] + bhh[n];
          ihp[st] = a; hhp[st] = b;
          s1 += a; q1 += a * a; s2 += b; q2 += b * b;
        }
        wave_red(s1); wave_red(q1); wave_red(s2); wave_red(q2);
        if (ln == 0) { red[wv*4] = s1; red[wv*4+1] = q1; red[wv*4+2] = s2; red[wv*4+3] = q2; }
        __syncthreads();
        s1 = 0; q1 = 0; s2 = 0; q2 = 0;
#pragma unroll
        for (int k = 0; k < 8; ++k) {
          s1 += red[k*4]; q1 += red[k*4+1]; s2 += red[k*4+2]; q2 += red[k*4+3];
        }
        __syncthreads();

        const float inv4h = 1.0f / 4096.0f;
        float m1 = s1 * inv4h, m2 = s2 * inv4h;
        float i1 = rsqrtf(q1 * inv4h - m1 * m1 + 1e-5f);
        float i2 = rsqrtf(q2 * inv4h - m2 * m2 + 1e-5f);

        float pre[8];
#pragma unroll
        for (int st = 0; st < 8; ++st) {
          int n = tid + 512 * st;
          pre[st] = gih[n] * (ihp[st] - m1) * i1 + beih[n] + ghh[n] * (hhp[st] - m2) * i2 + behh[n];
        }

        float cn[2], og[2];
        float s3 = 0, q3 = 0;
#pragma unroll
        for (int u = 0; u < 2; ++u) {
          int hidx = tid + 512 * u;
          float iG = 1.0f / (1.0f + __expf(-pre[u]));
          float fG = 1.0f / (1.0f + __expf(-pre[2 + u]));
          float oG = 1.0f / (1.0f + __expf(-pre[4 + u]));
          float gG = tanhf(pre[6 + u]);
          float c = fG * crow[hidx] + iG * gG;
          crow[hidx] = c;
          cn[u] = c; og[u] = oG;
          s3 += c; q3 += c * c;
        }
        wave_red(s3); wave_red(q3);
        if (ln == 0) { red[wv*4] = s3; red[wv*4+1] = q3; }
        __syncthreads();
        s3 = 0; q3 = 0;
#pragma unroll
        for (int k = 0; k < 8; ++k) { s3 += red[k*4]; q3 += red[k*4+1]; }

        const float invh = 1.0f / 1024.0f;
        float m3 = s3 * invh;
        float i3 = rsqrtf(q3 * invh - m3 * m3 + 1e-5f);
        int tY = layer ? (s - LAG_) : s;
        unsigned short* hHb = p.hH + layer * 65536 + (size_t)r * H_;
        unsigned short* hLb = p.hL + layer * 65536 + (size_t)r * H_;
        unsigned short* YH = p.XYhi + (size_t)tY * 65536 + (size_t)r * H_;
        unsigned short* YL = p.XYlo + (size_t)tY * 65536 + (size_t)r * H_;
#pragma unroll
        for (int u = 0; u < 2; ++u) {
          int hidx = tid + 512 * u;
          float hy = og[u] * tanhf((cn[u] - m3) * i3 * gho[hidx] + beho[hidx]);
          unsigned short hv = f2bf(hy);
          unsigned short lv = f2bf(hy - bf2f(hv));
          hHb[hidx] = hv; hLb[hidx] = lv;
          YH[hidx] = hv;  YL[hidx] = lv;
        }
      }
    }
    grid.sync();
  }
}

// ---------------------------------------------------------------------------
extern "C" void kernel_launch(void* const* d_in, const int* in_sizes, int n_in,
                              void* d_out, int out_size, void* d_ws, size_t ws_size,
                              hipStream_t stream) {
  const float* x    = (const float*)d_in[0];
  const float* w_ih = (const float*)d_in[1];
  const float* b_ih = (const float*)d_in[2];
  const float* w_hh = (const float*)d_in[3];
  const float* b_hh = (const float*)d_in[4];
  const float* g_ih = (const float*)d_in[5];
  const float* be_ih= (const float*)d_in[6];
  const float* g_hh = (const float*)d_in[7];
  const float* be_hh= (const float*)d_in[8];
  const float* g_ho = (const float*)d_in[9];
  const float* be_ho= (const float*)d_in[10];
  const float* fc_w = (const float*)d_in[11];
  const float* fc_b = (const float*)d_in[12];
  float* out = (float*)d_out;
  (void)ws_size; (void)in_sizes; (void)n_in; (void)out_size;

  // workspace carve-up (~231 MB)
  char* wsb = (char*)d_ws;
  size_t off = 0;
  unsigned short* wihHi = (unsigned short*)(wsb + off); off += 16777216;
  unsigned short* wihLo = (unsigned short*)(wsb + off); off += 16777216;
  unsigned short* whhHi = (unsigned short*)(wsb + off); off += 16777216;
  unsigned short* whhLo = (unsigned short*)(wsb + off); off += 16777216;
  unsigned short* fcHi  = (unsigned short*)(wsb + off); off += 2097152;
  unsigned short* fcLo  = (unsigned short*)(wsb + off); off += 2097152;
  unsigned short* XYhi  = (unsigned short*)(wsb + off); off += 67108864;
  unsigned short* XYlo  = (unsigned short*)(wsb + off); off += 67108864;
  float* P0             = (float*)(wsb + off); off += (size_t)16 * B_ * FH_ * 4; // 16 MB
  float* P1             = (float*)(wsb + off); off += (size_t)16 * B_ * FH_ * 4; // 16 MB
  float* G              = (float*)(wsb + off); off += (size_t)2 * B_ * FH_ * 4;  // 2 MB
  unsigned short* hH    = (unsigned short*)(wsb + off); off += 262144;
  unsigned short* hL    = (unsigned short*)(wsb + off); off += 262144;
  float* cst            = (float*)(wsb + off); off += 524288;
  // whhFrag (32 MB, fragment-order) aliases P0+P1: dead after LDS prologue.
  unsigned short* whhFrag = (unsigned short*)P0;

  // --- splits ---
  {
    int n4 = 2 * FH_ * D_ / 4;
    cast_split_k<<<(n4 + 255) / 256, 256, 0, stream>>>((const float4*)w_ih, (us4*)wihHi, (us4*)wihLo, n4);
    cast_split_k<<<(n4 + 255) / 256, 256, 0, stream>>>((const float4*)w_hh, (us4*)whhHi, (us4*)whhLo, n4);
    int nf = H_ * H_ / 4;
    cast_split_k<<<(nf + 255) / 256, 256, 0, stream>>>((const float4*)fc_w, (us4*)fcHi, (us4*)fcLo, nf);
    int nx = T_ * B_ * D_ / 4;
    transpose_split_k<<<nx / 256, 256, 0, stream>>>((const float4*)x, (us4*)XYhi, (us4*)XYlo);
    whh_frag_k<<<8192, 256, 0, stream>>>(whhHi, whhLo, whhFrag);
  }

  // --- state init ---
  hipMemsetAsync(hH, 0, 262144, stream);
  hipMemsetAsync(hL, 0, 262144, stream);
  hipMemsetAsync(cst, 0, 524288, stream);

  // --- persistent cooperative recurrence ---
  {
    static int attr_done = 0;
    hipFuncSetAttribute(reinterpret_cast<const void*>(lstm_persist_k),
                        hipFuncAttributeMaxDynamicSharedMemorySize, SMEM_TOTAL);
    (void)attr_done;
    LP prm;
    prm.XYhi = XYhi; prm.XYlo = XYlo;
    prm.wihHi = wihHi; prm.wihLo = wihLo;
    prm.whhFrag = whhFrag;
    prm.bih = b_ih; prm.bhh = b_hh; prm.gih = g_ih; prm.beih = be_ih;
    prm.ghh = g_hh; prm.behh = be_hh; prm.gho = g_ho; prm.beho = be_ho;
    prm.P0 = P0; prm.P1 = P1; prm.G = G;
    prm.hH = hH; prm.hL = hL; prm.cst = cst;
    void* args[] = { &prm };
    hipLaunchCooperativeKernel(reinterpret_cast<void*>(lstm_persist_k),
                               dim3(256), dim3(512), args, SMEM_TOTAL, stream);
  }

  // --- final FC: out[b][t][c] = Y1[t*B+b,:]·fc_w[c,:] + fc_b ---
  gemm3_fc_k<<<dim3(H_ / 128, (T_ * B_) / 128), 256, 0, stream>>>(
      XYhi, XYlo, fcHi, fcLo, fc_b, out, H_, H_);
}

// Round 5
// 23048.991 us; speedup vs baseline: 2.2781x; 2.0391x over previous
//
#include <hip/hip_runtime.h>

// ---------------------------------------------------------------------------
// LayerNorm-LSTM (depth=2) + FC, MI355X. Split-bf16 (hi/lo) 3-term MFMA.
// Round 5: launch-per-step (graph-captured), LAG-16 layer wavefront,
// full-K hh GEMM (no partials), L3-resident weights, per-row pointwise.
// ---------------------------------------------------------------------------

typedef __attribute__((ext_vector_type(8))) short short8;
typedef __attribute__((ext_vector_type(8))) __bf16 bf16x8;
typedef __attribute__((ext_vector_type(4))) float f32x4;
typedef __attribute__((ext_vector_type(4))) unsigned short us4;

#define B_ 64
#define T_ 512
#define D_ 1024
#define H_ 1024
#define FH_ 4096
#define LAG_ 16
#define NS_ (T_ + LAG_)        // 528 macro-steps
#define RCH_ (B_ * 16)         // 1024 rows per chunk window

static __device__ __forceinline__ unsigned short f2bf(float f) {
  unsigned int u = __builtin_bit_cast(unsigned int, f);
  u += 0x7FFFu + ((u >> 16) & 1u);   // round-to-nearest-even
  return (unsigned short)(u >> 16);
}
static __device__ __forceinline__ float bf2f(unsigned short u) {
  unsigned int x = ((unsigned int)u) << 16;
  return __builtin_bit_cast(float, x);
}

// ---------------- split-cast fp32 -> (hi, lo) bf16 ----------------
__global__ void cast_split_k(const float4* __restrict__ in,
                             us4* __restrict__ hi, us4* __restrict__ lo, int n4) {
  int i = blockIdx.x * 256 + threadIdx.x;
  if (i < n4) {
    float4 v = in[i];
    us4 h, l;
    h[0] = f2bf(v.x); l[0] = f2bf(v.x - bf2f(h[0]));
    h[1] = f2bf(v.y); l[1] = f2bf(v.y - bf2f(h[1]));
    h[2] = f2bf(v.z); l[2] = f2bf(v.z - bf2f(h[2]));
    h[3] = f2bf(v.w); l[3] = f2bf(v.w - bf2f(h[3]));
    hi[i] = h; lo[i] = l;
  }
}

// ------ transpose-split input [B][T][D] f32 -> [T][B][D] (hi, lo) bf16 -----
__global__ void transpose_split_k(const float4* __restrict__ x,
                                  us4* __restrict__ hi, us4* __restrict__ lo) {
  int i = blockIdx.x * 256 + threadIdx.x;   // over T*B*D/4
  int d4  = i & 255;
  int rem = i >> 8;
  int b = rem & 63;
  int t = rem >> 6;
  float4 v = x[((size_t)(b * T_ + t) << 8) + d4];
  us4 h, l;
  h[0] = f2bf(v.x); l[0] = f2bf(v.x - bf2f(h[0]));
  h[1] = f2bf(v.y); l[1] = f2bf(v.y - bf2f(h[1]));
  h[2] = f2bf(v.z); l[2] = f2bf(v.z - bf2f(h[2]));
  h[3] = f2bf(v.w); l[3] = f2bf(v.w - bf2f(h[3]));
  size_t o = ((size_t)(t * B_ + b) << 8) + d4;
  hi[o] = h; lo[o] = l;
}

// ---------------- 3-term split-bf16 GEMM (chunk projections + FC) ----------
// out[r,n] = (Ahi+Alo)[r,:]·(Whi+Wlo)[n,:] + bias[n]   (dropping lo·lo)
// 128x128 tile, BK=32, 4 waves (64x64 each). FCMODE: store out[b][t][n].
template <int FCMODE>
__global__ __launch_bounds__(256) void gemm3_k(
    const unsigned short* __restrict__ Ahi, const unsigned short* __restrict__ Alo,
    const unsigned short* __restrict__ Whi, const unsigned short* __restrict__ Wlo,
    const float* __restrict__ bias, float* __restrict__ out, int K, int N) {
  __shared__ unsigned short lAh[128 * 40];
  __shared__ unsigned short lAl[128 * 40];
  __shared__ unsigned short lWh[128 * 40];
  __shared__ unsigned short lWl[128 * 40];
  int tid = threadIdx.x;
  int l = tid & 63, w = tid >> 6;
  int r0 = blockIdx.y * 128, c0 = blockIdx.x * 128;
  int wr = (w >> 1) * 64, wc = (w & 1) * 64;
  int lr = l & 15, lk = (l >> 4) * 8;
  f32x4 acc[4][4] = {};
  int srow = tid >> 2;
  int scc  = (tid & 3) * 8;

  for (int kt = 0; kt < K; kt += 32) {
#pragma unroll
    for (int i = 0; i < 2; ++i) {
      int row = srow + i * 64;
      size_t aoff = (size_t)(r0 + row) * K + kt + scc;
      size_t woff = (size_t)(c0 + row) * K + kt + scc;
      *(short8*)&lAh[row * 40 + scc] = *(const short8*)(Ahi + aoff);
      *(short8*)&lAl[row * 40 + scc] = *(const short8*)(Alo + aoff);
      *(short8*)&lWh[row * 40 + scc] = *(const short8*)(Whi + woff);
      *(short8*)&lWl[row * 40 + scc] = *(const short8*)(Wlo + woff);
    }
    __syncthreads();
    bf16x8 ah[4], al[4], bh[4], bl[4];
#pragma unroll
    for (int mi = 0; mi < 4; ++mi) {
      ah[mi] = *(bf16x8*)&lAh[(wr + mi * 16 + lr) * 40 + lk];
      al[mi] = *(bf16x8*)&lAl[(wr + mi * 16 + lr) * 40 + lk];
    }
#pragma unroll
    for (int ni = 0; ni < 4; ++ni) {
      bh[ni] = *(bf16x8*)&lWh[(wc + ni * 16 + lr) * 40 + lk];
      bl[ni] = *(bf16x8*)&lWl[(wc + ni * 16 + lr) * 40 + lk];
    }
#pragma unroll
    for (int mi = 0; mi < 4; ++mi)
#pragma unroll
      for (int ni = 0; ni < 4; ++ni) {
        acc[mi][ni] = __builtin_amdgcn_mfma_f32_16x16x32_bf16(ah[mi], bh[ni], acc[mi][ni], 0, 0, 0);
        acc[mi][ni] = __builtin_amdgcn_mfma_f32_16x16x32_bf16(ah[mi], bl[ni], acc[mi][ni], 0, 0, 0);
        acc[mi][ni] = __builtin_amdgcn_mfma_f32_16x16x32_bf16(al[mi], bh[ni], acc[mi][ni], 0, 0, 0);
      }
    __syncthreads();
  }

#pragma unroll
  for (int mi = 0; mi < 4; ++mi)
#pragma unroll
    for (int ni = 0; ni < 4; ++ni)
#pragma unroll
      for (int reg = 0; reg < 4; ++reg) {
        int r = r0 + wr + mi * 16 + (l >> 4) * 4 + reg;
        int c = c0 + wc + ni * 16 + lr;
        float v = acc[mi][ni][reg] + bias[c];
        if (FCMODE) {
          int b = r & 63, t = r >> 6;
          out[((size_t)b * T_ + t) * (size_t)N + c] = v;
        } else {
          out[(size_t)r * N + c] = v;
        }
      }
}

// ---------------- per-step hh GEMM (full K, both layers, LAG wavefront) ----
// grid 256 x 512 thr: blk>>7 = layer, blk&127 = 32-col tile. Whh from L3.
__global__ __launch_bounds__(512) void hh_full_k(
    const unsigned short* __restrict__ hH, const unsigned short* __restrict__ hL,
    const unsigned short* __restrict__ whhHi, const unsigned short* __restrict__ whhLo,
    float* __restrict__ G, int s) {
  int layer = blockIdx.x >> 7;
  int t = layer ? (s - LAG_) : s;
  if (t < 0 || t >= T_) return;
  int jb = blockIdx.x & 127;
  int tid = threadIdx.x;
  int l = tid & 63, w = tid >> 6;
  int lr = l & 15, lk = (l >> 4) * 8, lq = l >> 4;
  int n0 = jb * 32 + (w >> 2) * 16;     // colfrag
  int m0 = (w & 3) * 16;                // rowfrag
  const unsigned short* hHb = hH + layer * 65536;
  const unsigned short* hLb = hL + layer * 65536;
  const unsigned short* Whi = whhHi + ((size_t)layer << 22);
  const unsigned short* Wlo = whhLo + ((size_t)layer << 22);
  f32x4 acc = {};
#pragma unroll 8
  for (int kt = 0; kt < 1024; kt += 32) {
    int k = kt + lk;
    bf16x8 ah = __builtin_bit_cast(bf16x8, *(const short8*)(hHb + (m0 + lr) * 1024 + k));
    bf16x8 al = __builtin_bit_cast(bf16x8, *(const short8*)(hLb + (m0 + lr) * 1024 + k));
    bf16x8 bh = __builtin_bit_cast(bf16x8, *(const short8*)(Whi + (size_t)(n0 + lr) * 1024 + k));
    bf16x8 bl = __builtin_bit_cast(bf16x8, *(const short8*)(Wlo + (size_t)(n0 + lr) * 1024 + k));
    acc = __builtin_amdgcn_mfma_f32_16x16x32_bf16(ah, bh, acc, 0, 0, 0);
    acc = __builtin_amdgcn_mfma_f32_16x16x32_bf16(ah, bl, acc, 0, 0, 0);
    acc = __builtin_amdgcn_mfma_f32_16x16x32_bf16(al, bh, acc, 0, 0, 0);
  }
  float* Gb = G + layer * (64 * FH_);
#pragma unroll
  for (int reg = 0; reg < 4; ++reg) {
    int row = m0 + lq * 4 + reg;
    Gb[(size_t)row * FH_ + n0 + lr] = acc[reg];
  }
}

// ---------------- per-step pointwise: LNx2 + gates + cell + cell-LN --------
// grid 128 x 256 thr: blk>>6 = layer, blk&63 = batch row. Full 4096 per block.
__device__ __forceinline__ void wave_red(float& v) {
#pragma unroll
  for (int o = 32; o; o >>= 1) v += __shfl_down(v, o);
}

__global__ __launch_bounds__(256) void pointwise_k(
    const float* __restrict__ P0, const float* __restrict__ P1,
    const float* __restrict__ G,
    const float* __restrict__ b_hh, const float* __restrict__ g_ih,
    const float* __restrict__ be_ih, const float* __restrict__ g_hh,
    const float* __restrict__ be_hh, const float* __restrict__ g_ho,
    const float* __restrict__ be_ho,
    float* __restrict__ cst,
    unsigned short* __restrict__ hH, unsigned short* __restrict__ hL,
    unsigned short* __restrict__ XYhi, unsigned short* __restrict__ XYlo,
    int s) {
  int layer = blockIdx.x >> 6;
  int t = layer ? (s - LAG_) : s;
  if (t < 0 || t >= T_) return;
  __shared__ float red[16];
  int r = blockIdx.x & 63, j = threadIdx.x;
  int wv = j >> 6, ln = j & 63;
  int slot = s & 15;   // (s-16)&15 == s&15
  const float* Pr = (layer ? P1 : P0) + ((size_t)slot * B_ + r) * FH_;
  const float* Gr = G + layer * (64 * FH_) + (size_t)r * FH_;
  const float* bhh = b_hh + layer * FH_;
  const float* gih = g_ih + layer * FH_;
  const float* beih= be_ih + layer * FH_;
  const float* ghh = g_hh + layer * FH_;
  const float* behh= be_hh + layer * FH_;
  const float* gho = g_ho + layer * H_;
  const float* beho= be_ho + layer * H_;
  float* crow = cst + layer * 65536 + (size_t)r * H_;

  float ihp[16], hhp[16];
  float s1 = 0, q1 = 0, s2 = 0, q2 = 0;
#pragma unroll
  for (int st = 0; st < 16; ++st) {
    int n = j + 256 * st;
    float a = Pr[n];
    float b = Gr[n] + bhh[n];
    ihp[st] = a; hhp[st] = b;
    s1 += a; q1 += a * a; s2 += b; q2 += b * b;
  }
  wave_red(s1); wave_red(q1); wave_red(s2); wave_red(q2);
  if (ln == 0) { red[wv * 4] = s1; red[wv * 4 + 1] = q1; red[wv * 4 + 2] = s2; red[wv * 4 + 3] = q2; }
  __syncthreads();
  s1 = red[0] + red[4] + red[8] + red[12];
  q1 = red[1] + red[5] + red[9] + red[13];
  s2 = red[2] + red[6] + red[10] + red[14];
  q2 = red[3] + red[7] + red[11] + red[15];
  __syncthreads();

  const float inv4h = 1.0f / 4096.0f;
  float m1 = s1 * inv4h, m2 = s2 * inv4h;
  float i1 = rsqrtf(q1 * inv4h - m1 * m1 + 1e-5f);
  float i2 = rsqrtf(q2 * inv4h - m2 * m2 + 1e-5f);

  float pre[16];
#pragma unroll
  for (int st = 0; st < 16; ++st) {
    int n = j + 256 * st;
    pre[st] = gih[n] * (ihp[st] - m1) * i1 + beih[n] + ghh[n] * (hhp[st] - m2) * i2 + behh[n];
  }

  float cn[4], og[4];
  float s3 = 0, q3 = 0;
#pragma unroll
  for (int u = 0; u < 4; ++u) {
    int hidx = j + 256 * u;
    float iG = 1.0f / (1.0f + __expf(-pre[u]));
    float fG = 1.0f / (1.0f + __expf(-pre[u + 4]));
    float oG = 1.0f / (1.0f + __expf(-pre[u + 8]));
    float gG = tanhf(pre[u + 12]);
    float c = fG * crow[hidx] + iG * gG;
    crow[hidx] = c;
    cn[u] = c; og[u] = oG;
    s3 += c; q3 += c * c;
  }
  wave_red(s3); wave_red(q3);
  if (ln == 0) { red[wv * 4] = s3; red[wv * 4 + 1] = q3; }
  __syncthreads();
  s3 = red[0] + red[4] + red[8] + red[12];
  q3 = red[1] + red[5] + red[9] + red[13];

  const float invh = 1.0f / 1024.0f;
  float m3 = s3 * invh;
  float i3 = rsqrtf(q3 * invh - m3 * m3 + 1e-5f);
  unsigned short* hHb = hH + layer * 65536 + (size_t)r * H_;
  unsigned short* hLb = hL + layer * 65536 + (size_t)r * H_;
  unsigned short* YH = XYhi + ((size_t)t * B_ + r) * H_;
  unsigned short* YL = XYlo + ((size_t)t * B_ + r) * H_;
#pragma unroll
  for (int u = 0; u < 4; ++u) {
    int hidx = j + 256 * u;
    float hy = og[u] * tanhf((cn[u] - m3) * i3 * gho[hidx] + beho[hidx]);
    unsigned short hv = f2bf(hy);
    unsigned short lv = f2bf(hy - bf2f(hv));
    hHb[hidx] = hv; hLb[hidx] = lv;
    YH[hidx] = hv;  YL[hidx] = lv;
  }
}

// ---------------------------------------------------------------------------
extern "C" void kernel_launch(void* const* d_in, const int* in_sizes, int n_in,
                              void* d_out, int out_size, void* d_ws, size_t ws_size,
                              hipStream_t stream) {
  const float* x    = (const float*)d_in[0];
  const float* w_ih = (const float*)d_in[1];
  const float* b_ih = (const float*)d_in[2];
  const float* w_hh = (const float*)d_in[3];
  const float* b_hh = (const float*)d_in[4];
  const float* g_ih = (const float*)d_in[5];
  const float* be_ih= (const float*)d_in[6];
  const float* g_hh = (const float*)d_in[7];
  const float* be_hh= (const float*)d_in[8];
  const float* g_ho = (const float*)d_in[9];
  const float* be_ho= (const float*)d_in[10];
  const float* fc_w = (const float*)d_in[11];
  const float* fc_b = (const float*)d_in[12];
  float* out = (float*)d_out;
  (void)ws_size; (void)in_sizes; (void)n_in; (void)out_size;

  // workspace carve-up (~231 MB)
  char* wsb = (char*)d_ws;
  size_t off = 0;
  unsigned short* wihHi = (unsigned short*)(wsb + off); off += 16777216;
  unsigned short* wihLo = (unsigned short*)(wsb + off); off += 16777216;
  unsigned short* whhHi = (unsigned short*)(wsb + off); off += 16777216;
  unsigned short* whhLo = (unsigned short*)(wsb + off); off += 16777216;
  unsigned short* fcHi  = (unsigned short*)(wsb + off); off += 2097152;
  unsigned short* fcLo  = (unsigned short*)(wsb + off); off += 2097152;
  unsigned short* XYhi  = (unsigned short*)(wsb + off); off += 67108864;   // [T][64][1024] X->Y0->Y1
  unsigned short* XYlo  = (unsigned short*)(wsb + off); off += 67108864;
  float* P0             = (float*)(wsb + off); off += (size_t)16 * B_ * FH_ * 4; // 16 MB
  float* P1             = (float*)(wsb + off); off += (size_t)16 * B_ * FH_ * 4; // 16 MB
  float* G              = (float*)(wsb + off); off += (size_t)2 * B_ * FH_ * 4;  // 2 MB
  unsigned short* hH    = (unsigned short*)(wsb + off); off += 262144;
  unsigned short* hL    = (unsigned short*)(wsb + off); off += 262144;
  float* cst            = (float*)(wsb + off); off += 524288;

  // --- splits ---
  {
    int n4 = 2 * FH_ * D_ / 4;
    cast_split_k<<<(n4 + 255) / 256, 256, 0, stream>>>((const float4*)w_ih, (us4*)wihHi, (us4*)wihLo, n4);
    cast_split_k<<<(n4 + 255) / 256, 256, 0, stream>>>((const float4*)w_hh, (us4*)whhHi, (us4*)whhLo, n4);
    int nf = H_ * H_ / 4;
    cast_split_k<<<(nf + 255) / 256, 256, 0, stream>>>((const float4*)fc_w, (us4*)fcHi, (us4*)fcLo, nf);
    int nx = T_ * B_ * D_ / 4;
    transpose_split_k<<<nx / 256, 256, 0, stream>>>((const float4*)x, (us4*)XYhi, (us4*)XYlo);
  }

  // --- state init ---
  hipMemsetAsync(hH, 0, 262144, stream);
  hipMemsetAsync(hL, 0, 262144, stream);
  hipMemsetAsync(cst, 0, 524288, stream);

  // --- recurrence: launch-per-step, LAG-16 layer wavefront ---
  for (int s = 0; s < NS_; ++s) {
    if ((s & 15) == 0) {
      if (s < T_) {
        // P0 <- X rows [s..s+16) x Wih0^T + b_ih0
        gemm3_k<0><<<dim3(FH_ / 128, RCH_ / 128), 256, 0, stream>>>(
            XYhi + (size_t)s * B_ * D_, XYlo + (size_t)s * B_ * D_,
            wihHi, wihLo, b_ih, P0, D_, FH_);
      }
      if (s >= LAG_) {
        // P1 <- Y0 rows [s-16..s) x Wih1^T + b_ih1
        gemm3_k<0><<<dim3(FH_ / 128, RCH_ / 128), 256, 0, stream>>>(
            XYhi + (size_t)(s - LAG_) * B_ * D_, XYlo + (size_t)(s - LAG_) * B_ * D_,
            wihHi + (1 << 22), wihLo + (1 << 22), b_ih + FH_, P1, D_, FH_);
      }
    }
    hh_full_k<<<256, 512, 0, stream>>>(hH, hL, whhHi, whhLo, G, s);
    pointwise_k<<<128, 256, 0, stream>>>(P0, P1, G, b_hh, g_ih, be_ih, g_hh, be_hh,
                                         g_ho, be_ho, cst, hH, hL, XYhi, XYlo, s);
  }

  // --- final FC: out[b][t][c] = Y1[t*B+b,:]·fc_w[c,:] + fc_b ---
  gemm3_k<1><<<dim3(H_ / 128, (T_ * B_) / 128), 256, 0, stream>>>(
      XYhi, XYlo, fcHi, fcLo, fc_b, out, H_, H_);
}

// Round 6
// 17991.048 us; speedup vs baseline: 2.9185x; 1.2811x over previous
//
#include <hip/hip_runtime.h>

// ---------------------------------------------------------------------------
// LayerNorm-LSTM (depth=2) + FC, MI355X. Split-bf16 (hi/lo) 3-term MFMA.
// Round 6: per-step launches + LDS-staged hh GEMM. Whh is pre-arranged in
// MFMA fragment order (64KB slice per (layer,16-col) block) and staged via
// async global_load_lds (width 16) -> sequential coalesced fetch, no dup.
// ---------------------------------------------------------------------------

typedef __attribute__((ext_vector_type(8))) short short8;
typedef __attribute__((ext_vector_type(8))) __bf16 bf16x8;
typedef __attribute__((ext_vector_type(4))) float f32x4;
typedef __attribute__((ext_vector_type(4))) unsigned short us4;

#define B_ 64
#define T_ 512
#define D_ 1024
#define H_ 1024
#define FH_ 4096
#define LAG_ 16
#define NS_ (T_ + LAG_)        // 528 macro-steps
#define RCH_ (B_ * 16)         // 1024 rows per chunk window

typedef const __attribute__((address_space(1))) unsigned int* gas_ptr;
typedef __attribute__((address_space(3))) unsigned int* las_ptr;
#define GLOAD_LDS16(g, l) \
  __builtin_amdgcn_global_load_lds((gas_ptr)(g), (las_ptr)(l), 16, 0, 0)

static __device__ __forceinline__ unsigned short f2bf(float f) {
  unsigned int u = __builtin_bit_cast(unsigned int, f);
  u += 0x7FFFu + ((u >> 16) & 1u);   // round-to-nearest-even
  return (unsigned short)(u >> 16);
}
static __device__ __forceinline__ float bf2f(unsigned short u) {
  unsigned int x = ((unsigned int)u) << 16;
  return __builtin_bit_cast(float, x);
}

// ---------------- split-cast fp32 -> (hi, lo) bf16 ----------------
__global__ void cast_split_k(const float4* __restrict__ in,
                             us4* __restrict__ hi, us4* __restrict__ lo, int n4) {
  int i = blockIdx.x * 256 + threadIdx.x;
  if (i < n4) {
    float4 v = in[i];
    us4 h, l;
    h[0] = f2bf(v.x); l[0] = f2bf(v.x - bf2f(h[0]));
    h[1] = f2bf(v.y); l[1] = f2bf(v.y - bf2f(h[1]));
    h[2] = f2bf(v.z); l[2] = f2bf(v.z - bf2f(h[2]));
    h[3] = f2bf(v.w); l[3] = f2bf(v.w - bf2f(h[3]));
    hi[i] = h; lo[i] = l;
  }
}

// ------ transpose-split input [B][T][D] f32 -> [T][B][D] (hi, lo) bf16 -----
__global__ void transpose_split_k(const float4* __restrict__ x,
                                  us4* __restrict__ hi, us4* __restrict__ lo) {
  int i = blockIdx.x * 256 + threadIdx.x;   // over T*B*D/4
  int d4  = i & 255;
  int rem = i >> 8;
  int b = rem & 63;
  int t = rem >> 6;
  float4 v = x[((size_t)(b * T_ + t) << 8) + d4];
  us4 h, l;
  h[0] = f2bf(v.x); l[0] = f2bf(v.x - bf2f(h[0]));
  h[1] = f2bf(v.y); l[1] = f2bf(v.y - bf2f(h[1]));
  h[2] = f2bf(v.z); l[2] = f2bf(v.z - bf2f(h[2]));
  h[3] = f2bf(v.w); l[3] = f2bf(v.w - bf2f(h[3]));
  size_t o = ((size_t)(t * B_ + b) << 8) + d4;
  hi[o] = h; lo[o] = l;
}

// ------ build fragment-ordered split Whh straight from fp32 ---------------
// frag chunk index i (16B each): slice sl=i>>12 (layer*256+j), sel=(i>>11)&1,
// kc=(i>>6)&31, lane=i&63. Lane data = W[j*16+(lane&15)][kc*32+(lane>>4)*8 ..+7].
__global__ void whh_frag_k(const float* __restrict__ w_hh,
                           unsigned short* __restrict__ frag) {
  int i = blockIdx.x * 256 + threadIdx.x;    // 2,097,152 chunks
  int sl   = i >> 12;
  int rem  = i & 4095;
  int sel  = rem >> 11;
  int kc   = (rem >> 6) & 31;
  int lane = rem & 63;
  int layer = sl >> 8, j = sl & 255;
  int col = j * 16 + (lane & 15);
  int kof = kc * 32 + (lane >> 4) * 8;
  const float* src = w_hh + ((size_t)layer * FH_ + col) * 1024 + kof;
  short8 o;
#pragma unroll
  for (int e = 0; e < 8; ++e) {
    float v = src[e];
    unsigned short h = f2bf(v);
    o[e] = sel ? (short)f2bf(v - bf2f(h)) : (short)h;
  }
  *(short8*)(frag + (size_t)i * 8) = o;
}

// ---------------- 3-term split-bf16 GEMM (chunk projections + FC) ----------
template <int FCMODE>
__global__ __launch_bounds__(256) void gemm3_k(
    const unsigned short* __restrict__ Ahi, const unsigned short* __restrict__ Alo,
    const unsigned short* __restrict__ Whi, const unsigned short* __restrict__ Wlo,
    const float* __restrict__ bias, float* __restrict__ out, int K, int N) {
  __shared__ unsigned short lAh[128 * 40];
  __shared__ unsigned short lAl[128 * 40];
  __shared__ unsigned short lWh[128 * 40];
  __shared__ unsigned short lWl[128 * 40];
  int tid = threadIdx.x;
  int l = tid & 63, w = tid >> 6;
  int r0 = blockIdx.y * 128, c0 = blockIdx.x * 128;
  int wr = (w >> 1) * 64, wc = (w & 1) * 64;
  int lr = l & 15, lk = (l >> 4) * 8;
  f32x4 acc[4][4] = {};
  int srow = tid >> 2;
  int scc  = (tid & 3) * 8;

  for (int kt = 0; kt < K; kt += 32) {
#pragma unroll
    for (int i = 0; i < 2; ++i) {
      int row = srow + i * 64;
      size_t aoff = (size_t)(r0 + row) * K + kt + scc;
      size_t woff = (size_t)(c0 + row) * K + kt + scc;
      *(short8*)&lAh[row * 40 + scc] = *(const short8*)(Ahi + aoff);
      *(short8*)&lAl[row * 40 + scc] = *(const short8*)(Alo + aoff);
      *(short8*)&lWh[row * 40 + scc] = *(const short8*)(Whi + woff);
      *(short8*)&lWl[row * 40 + scc] = *(const short8*)(Wlo + woff);
    }
    __syncthreads();
    bf16x8 ah[4], al[4], bh[4], bl[4];
#pragma unroll
    for (int mi = 0; mi < 4; ++mi) {
      ah[mi] = *(bf16x8*)&lAh[(wr + mi * 16 + lr) * 40 + lk];
      al[mi] = *(bf16x8*)&lAl[(wr + mi * 16 + lr) * 40 + lk];
    }
#pragma unroll
    for (int ni = 0; ni < 4; ++ni) {
      bh[ni] = *(bf16x8*)&lWh[(wc + ni * 16 + lr) * 40 + lk];
      bl[ni] = *(bf16x8*)&lWl[(wc + ni * 16 + lr) * 40 + lk];
    }
#pragma unroll
    for (int mi = 0; mi < 4; ++mi)
#pragma unroll
      for (int ni = 0; ni < 4; ++ni) {
        acc[mi][ni] = __builtin_amdgcn_mfma_f32_16x16x32_bf16(ah[mi], bh[ni], acc[mi][ni], 0, 0, 0);
        acc[mi][ni] = __builtin_amdgcn_mfma_f32_16x16x32_bf16(ah[mi], bl[ni], acc[mi][ni], 0, 0, 0);
        acc[mi][ni] = __builtin_amdgcn_mfma_f32_16x16x32_bf16(al[mi], bh[ni], acc[mi][ni], 0, 0, 0);
      }
    __syncthreads();
  }

#pragma unroll
  for (int mi = 0; mi < 4; ++mi)
#pragma unroll
    for (int ni = 0; ni < 4; ++ni)
#pragma unroll
      for (int reg = 0; reg < 4; ++reg) {
        int r = r0 + wr + mi * 16 + (l >> 4) * 4 + reg;
        int c = c0 + wc + ni * 16 + lr;
        float v = acc[mi][ni][reg] + bias[c];
        if (FCMODE) {
          int b = r & 63, t = r >> 6;
          out[((size_t)b * T_ + t) * (size_t)N + c] = v;
        } else {
          out[(size_t)r * N + c] = v;
        }
      }
}

// ---------------- per-step hh GEMM with LDS-staged Whh ---------------------
// grid 512 x 256 thr: blk>>8 = layer, blk&255 = 16-col slice. 64KB dyn LDS.
__global__ __launch_bounds__(256) void hh_lds_k(
    const unsigned short* __restrict__ hH, const unsigned short* __restrict__ hL,
    const unsigned short* __restrict__ whhFrag,
    float* __restrict__ G, int s) {
  int layer = blockIdx.x >> 8;
  int t = layer ? (s - LAG_) : s;
  if (t < 0 || t >= T_) return;
  int j = blockIdx.x & 255;
  extern __shared__ char smem[];
  unsigned short* wl = (unsigned short*)smem;
  int tid = threadIdx.x;
  int l = tid & 63, w = tid >> 6;
  int lr = l & 15, lk = (l >> 4) * 8, lq = l >> 4;

  // ---- async stage: 4096 x 16B chunks, lane-linear ----
  const unsigned short* gsrc = whhFrag + (((size_t)(layer * 256 + j)) << 15);
#pragma unroll
  for (int r = 0; r < 16; ++r) {
    int c = r * 256 + tid;                       // chunk this thread fetches
    GLOAD_LDS16(gsrc + (size_t)c * 8, wl + (size_t)(r * 256 + w * 64) * 8);
  }

  // ---- h fragments can load while staging is in flight ----
  const unsigned short* hHb = hH + layer * 65536;
  const unsigned short* hLb = hL + layer * 65536;
  int m0 = w * 16;

  __syncthreads();   // drains vmcnt(0): staging + any h loads complete

  f32x4 acc = {};
#pragma unroll 8
  for (int kc = 0; kc < 32; ++kc) {
    int k = kc * 32 + lk;
    bf16x8 ah = __builtin_bit_cast(bf16x8, *(const short8*)(hHb + (m0 + lr) * 1024 + k));
    bf16x8 al = __builtin_bit_cast(bf16x8, *(const short8*)(hLb + (m0 + lr) * 1024 + k));
    bf16x8 bh = __builtin_bit_cast(bf16x8, *(const short8*)&wl[(size_t)(kc * 64 + l) * 8]);
    bf16x8 bl = __builtin_bit_cast(bf16x8, *(const short8*)&wl[(size_t)(2048 + kc * 64 + l) * 8]);
    acc = __builtin_amdgcn_mfma_f32_16x16x32_bf16(ah, bh, acc, 0, 0, 0);
    acc = __builtin_amdgcn_mfma_f32_16x16x32_bf16(ah, bl, acc, 0, 0, 0);
    acc = __builtin_amdgcn_mfma_f32_16x16x32_bf16(al, bh, acc, 0, 0, 0);
  }
  float* Gb = G + layer * (64 * FH_);
  int n0 = j * 16;
#pragma unroll
  for (int reg = 0; reg < 4; ++reg) {
    int row = m0 + lq * 4 + reg;
    Gb[(size_t)row * FH_ + n0 + lr] = acc[reg];
  }
}

// ---------------- per-step pointwise: LNx2 + gates + cell + cell-LN --------
__device__ __forceinline__ void wave_red(float& v) {
#pragma unroll
  for (int o = 32; o; o >>= 1) v += __shfl_down(v, o);
}

__global__ __launch_bounds__(256) void pointwise_k(
    const float* __restrict__ P0, const float* __restrict__ P1,
    const float* __restrict__ G,
    const float* __restrict__ b_hh, const float* __restrict__ g_ih,
    const float* __restrict__ be_ih, const float* __restrict__ g_hh,
    const float* __restrict__ be_hh, const float* __restrict__ g_ho,
    const float* __restrict__ be_ho,
    float* __restrict__ cst,
    unsigned short* __restrict__ hH, unsigned short* __restrict__ hL,
    unsigned short* __restrict__ XYhi, unsigned short* __restrict__ XYlo,
    int s) {
  int layer = blockIdx.x >> 6;
  int t = layer ? (s - LAG_) : s;
  if (t < 0 || t >= T_) return;
  __shared__ float red[16];
  int r = blockIdx.x & 63, j = threadIdx.x;
  int wv = j >> 6, ln = j & 63;
  int slot = s & 15;
  const float* Pr = (layer ? P1 : P0) + ((size_t)slot * B_ + r) * FH_;
  const float* Gr = G + layer * (64 * FH_) + (size_t)r * FH_;
  const float* bhh = b_hh + layer * FH_;
  const float* gih = g_ih + layer * FH_;
  const float* beih= be_ih + layer * FH_;
  const float* ghh = g_hh + layer * FH_;
  const float* behh= be_hh + layer * FH_;
  const float* gho = g_ho + layer * H_;
  const float* beho= be_ho + layer * H_;
  float* crow = cst + layer * 65536 + (size_t)r * H_;

  float ihp[16], hhp[16];
  float s1 = 0, q1 = 0, s2 = 0, q2 = 0;
#pragma unroll
  for (int st = 0; st < 16; ++st) {
    int n = j + 256 * st;
    float a = Pr[n];
    float b = Gr[n] + bhh[n];
    ihp[st] = a; hhp[st] = b;
    s1 += a; q1 += a * a; s2 += b; q2 += b * b;
  }
  wave_red(s1); wave_red(q1); wave_red(s2); wave_red(q2);
  if (ln == 0) { red[wv * 4] = s1; red[wv * 4 + 1] = q1; red[wv * 4 + 2] = s2; red[wv * 4 + 3] = q2; }
  __syncthreads();
  s1 = red[0] + red[4] + red[8] + red[12];
  q1 = red[1] + red[5] + red[9] + red[13];
  s2 = red[2] + red[6] + red[10] + red[14];
  q2 = red[3] + red[7] + red[11] + red[15];
  __syncthreads();

  const float inv4h = 1.0f / 4096.0f;
  float m1 = s1 * inv4h, m2 = s2 * inv4h;
  float i1 = rsqrtf(q1 * inv4h - m1 * m1 + 1e-5f);
  float i2 = rsqrtf(q2 * inv4h - m2 * m2 + 1e-5f);

  float pre[16];
#pragma unroll
  for (int st = 0; st < 16; ++st) {
    int n = j + 256 * st;
    pre[st] = gih[n] * (ihp[st] - m1) * i1 + beih[n] + ghh[n] * (hhp[st] - m2) * i2 + behh[n];
  }

  float cn[4], og[4];
  float s3 = 0, q3 = 0;
#pragma unroll
  for (int u = 0; u < 4; ++u) {
    int hidx = j + 256 * u;
    float iG = 1.0f / (1.0f + __expf(-pre[u]));
    float fG = 1.0f / (1.0f + __expf(-pre[u + 4]));
    float oG = 1.0f / (1.0f + __expf(-pre[u + 8]));
    float gG = tanhf(pre[u + 12]);
    float c = fG * crow[hidx] + iG * gG;
    crow[hidx] = c;
    cn[u] = c; og[u] = oG;
    s3 += c; q3 += c * c;
  }
  wave_red(s3); wave_red(q3);
  if (ln == 0) { red[wv * 4] = s3; red[wv * 4 + 1] = q3; }
  __syncthreads();
  s3 = red[0] + red[4] + red[8] + red[12];
  q3 = red[1] + red[5] + red[9] + red[13];

  const float invh = 1.0f / 1024.0f;
  float m3 = s3 * invh;
  float i3 = rsqrtf(q3 * invh - m3 * m3 + 1e-5f);
  unsigned short* hHb = hH + layer * 65536 + (size_t)r * H_;
  unsigned short* hLb = hL + layer * 65536 + (size_t)r * H_;
  unsigned short* YH = XYhi + ((size_t)t * B_ + r) * H_;
  unsigned short* YL = XYlo + ((size_t)t * B_ + r) * H_;
#pragma unroll
  for (int u = 0; u < 4; ++u) {
    int hidx = j + 256 * u;
    float hy = og[u] * tanhf((cn[u] - m3) * i3 * gho[hidx] + beho[hidx]);
    unsigned short hv = f2bf(hy);
    unsigned short lv = f2bf(hy - bf2f(hv));
    hHb[hidx] = hv; hLb[hidx] = lv;
    YH[hidx] = hv;  YL[hidx] = lv;
  }
}

// ---------------------------------------------------------------------------
extern "C" void kernel_launch(void* const* d_in, const int* in_sizes, int n_in,
                              void* d_out, int out_size, void* d_ws, size_t ws_size,
                              hipStream_t stream) {
  const float* x    = (const float*)d_in[0];
  const float* w_ih = (const float*)d_in[1];
  const float* b_ih = (const float*)d_in[2];
  const float* w_hh = (const float*)d_in[3];
  const float* b_hh = (const float*)d_in[4];
  const float* g_ih = (const float*)d_in[5];
  const float* be_ih= (const float*)d_in[6];
  const float* g_hh = (const float*)d_in[7];
  const float* be_hh= (const float*)d_in[8];
  const float* g_ho = (const float*)d_in[9];
  const float* be_ho= (const float*)d_in[10];
  const float* fc_w = (const float*)d_in[11];
  const float* fc_b = (const float*)d_in[12];
  float* out = (float*)d_out;
  (void)ws_size; (void)in_sizes; (void)n_in; (void)out_size;

  // workspace carve-up (~231 MB)
  char* wsb = (char*)d_ws;
  size_t off = 0;
  unsigned short* wihHi  = (unsigned short*)(wsb + off); off += 16777216;
  unsigned short* wihLo  = (unsigned short*)(wsb + off); off += 16777216;
  unsigned short* whhFrag= (unsigned short*)(wsb + off); off += 33554432;  // frag-order hi/lo
  unsigned short* fcHi   = (unsigned short*)(wsb + off); off += 2097152;
  unsigned short* fcLo   = (unsigned short*)(wsb + off); off += 2097152;
  unsigned short* XYhi   = (unsigned short*)(wsb + off); off += 67108864;  // [T][64][1024] X->Y0->Y1
  unsigned short* XYlo   = (unsigned short*)(wsb + off); off += 67108864;
  float* P0              = (float*)(wsb + off); off += (size_t)16 * B_ * FH_ * 4; // 16 MB
  float* P1              = (float*)(wsb + off); off += (size_t)16 * B_ * FH_ * 4; // 16 MB
  float* G               = (float*)(wsb + off); off += (size_t)2 * B_ * FH_ * 4;  // 2 MB
  unsigned short* hH     = (unsigned short*)(wsb + off); off += 262144;
  unsigned short* hL     = (unsigned short*)(wsb + off); off += 262144;
  float* cst             = (float*)(wsb + off); off += 524288;

  // --- weight prep ---
  {
    int n4 = 2 * FH_ * D_ / 4;
    cast_split_k<<<(n4 + 255) / 256, 256, 0, stream>>>((const float4*)w_ih, (us4*)wihHi, (us4*)wihLo, n4);
    int nf = H_ * H_ / 4;
    cast_split_k<<<(nf + 255) / 256, 256, 0, stream>>>((const float4*)fc_w, (us4*)fcHi, (us4*)fcLo, nf);
    int nx = T_ * B_ * D_ / 4;
    transpose_split_k<<<nx / 256, 256, 0, stream>>>((const float4*)x, (us4*)XYhi, (us4*)XYlo);
    whh_frag_k<<<8192, 256, 0, stream>>>(w_hh, whhFrag);
  }

  // --- state init ---
  hipMemsetAsync(hH, 0, 262144, stream);
  hipMemsetAsync(hL, 0, 262144, stream);
  hipMemsetAsync(cst, 0, 524288, stream);

  // allow 64KB dynamic LDS for the hh kernel
  hipFuncSetAttribute(reinterpret_cast<const void*>(hh_lds_k),
                      hipFuncAttributeMaxDynamicSharedMemorySize, 65536);

  // --- recurrence: launch-per-step, LAG-16 layer wavefront ---
  for (int s = 0; s < NS_; ++s) {
    if ((s & 15) == 0) {
      if (s < T_) {
        gemm3_k<0><<<dim3(FH_ / 128, RCH_ / 128), 256, 0, stream>>>(
            XYhi + (size_t)s * B_ * D_, XYlo + (size_t)s * B_ * D_,
            wihHi, wihLo, b_ih, P0, D_, FH_);
      }
      if (s >= LAG_) {
        gemm3_k<0><<<dim3(FH_ / 128, RCH_ / 128), 256, 0, stream>>>(
            XYhi + (size_t)(s - LAG_) * B_ * D_, XYlo + (size_t)(s - LAG_) * B_ * D_,
            wihHi + (1 << 22), wihLo + (1 << 22), b_ih + FH_, P1, D_, FH_);
      }
    }
    hh_lds_k<<<512, 256, 65536, stream>>>(hH, hL, whhFrag, G, s);
    pointwise_k<<<128, 256, 0, stream>>>(P0, P1, G, b_hh, g_ih, be_ih, g_hh, be_hh,
                                         g_ho, be_ho, cst, hH, hL, XYhi, XYlo, s);
  }

  // --- final FC: out[b][t][c] = Y1[t*B+b,:]·fc_w[c,:] + fc_b ---
  gemm3_k<1><<<dim3(H_ / 128, (T_ * B_) / 128), 256, 0, stream>>>(
      XYhi, XYlo, fcHi, fcLo, fc_b, out, H_, H_);
}